// Round 2
// baseline (307.879 us; speedup 1.0000x reference)
//
#include <hip/hip_runtime.h>
#include <hip/hip_cooperative_groups.h>
#include <cstddef>

namespace cg = cooperative_groups;
typedef unsigned long long ull;

#define HH 1024
#define WW 2048
#define NPIX (HH * WW)
#define MAXC 200
#define GRIDB 256
#define BLKT 1024
#define NTHR (GRIDB * BLKT)
#define PXT (NPIX / NTHR)   // 8 pixels per thread, consecutive

struct Hdr {
  int count, remaining, stop, seed_idx;
  float c0, c1, s0, s1;
  int ps, uip;
  int prev[MAXC], now[MAXC], bad[MAXC];
};

union F8 { float4 v[2]; float f[8]; };
union I8 { int4 v[2]; int f[8]; };

__device__ inline ull shfl_down_u64(ull v, int o) {
  unsigned lo = (unsigned)v, hi = (unsigned)(v >> 32);
  lo = __shfl_down(lo, o, 64);
  hi = __shfl_down(hi, o, 64);
  return ((ull)hi << 32) | lo;
}

// Result valid on thread 0 of the block only.
__device__ inline ull blk_red_max(ull v, ull* lred) {
  #pragma unroll
  for (int o = 32; o > 0; o >>= 1) { ull u = shfl_down_u64(v, o); if (u > v) v = u; }
  int wid = threadIdx.x >> 6, lane = threadIdx.x & 63;
  __syncthreads();
  if (lane == 0) lred[wid] = v;
  __syncthreads();
  if (threadIdx.x == 0) {
    int nw = blockDim.x >> 6;
    for (int i = 1; i < nw; i++) { ull u = lred[i]; if (u > v) v = u; }
  }
  return v;
}

__device__ inline ull blk_red_add(ull v, ull* lred) {
  #pragma unroll
  for (int o = 32; o > 0; o >>= 1) v += shfl_down_u64(v, o);
  int wid = threadIdx.x >> 6, lane = threadIdx.x & 63;
  __syncthreads();
  if (lane == 0) lred[wid] = v;
  __syncthreads();
  if (threadIdx.x == 0) {
    int nw = blockDim.x >> 6;
    for (int i = 1; i < nw; i++) v += lred[i];
  }
  return v;
}

__global__ void k_init(Hdr* hdr) {
  int* p = (int*)hdr;
  const int n = (int)(sizeof(Hdr) / 4);
  for (int i = threadIdx.x; i < n; i += blockDim.x) p[i] = 0;
  if (threadIdx.x == 0) hdr->count = 1;  // thread 0 also zeroed p[0]; same thread, ordered
}

__global__ __launch_bounds__(BLKT) void k_pre(
    const float* __restrict__ pred,
    float* __restrict__ se0, float* __restrict__ se1,
    float* __restrict__ smw, unsigned char* __restrict__ inst,
    Hdr* hdr)
{
  __shared__ ull lred[BLKT / 64];
  const int tid = blockIdx.x * BLKT + threadIdx.x;
  const int base = tid * PXT;
  const float dxs = 2.0f / 2047.0f;   // jnp.linspace(0,2,2048) step, f32
  const float dys = 1.0f / 1023.0f;   // jnp.linspace(0,1,1024) step, f32
  F8 P0, P1, P5, P6, O0, O1, SM;
  P0.v[0] = *(const float4*)(pred + base);            P0.v[1] = *(const float4*)(pred + base + 4);
  P1.v[0] = *(const float4*)(pred + NPIX + base);     P1.v[1] = *(const float4*)(pred + NPIX + base + 4);
  P5.v[0] = *(const float4*)(pred + 5 * NPIX + base); P5.v[1] = *(const float4*)(pred + 5 * NPIX + base + 4);
  P6.v[0] = *(const float4*)(pred + 6 * NPIX + base); P6.v[1] = *(const float4*)(pred + 6 * NPIX + base + 4);
  const int h = base >> 11;          // W = 2048
  const int wb = base & (WW - 1);    // 8 | base, so all 8 px share a row
  const float yv = __fmul_rn((float)h, dys);
  int cnt = 0;
  #pragma unroll
  for (int j = 0; j < PXT; j++) {
    O0.f[j] = __fadd_rn(tanhf(P0.f[j]), __fmul_rn((float)(wb + j), dxs));
    O1.f[j] = __fadd_rn(tanhf(P1.f[j]), yv);
    float a = P5.f[j], b = P6.f[j];
    float mx = fmaxf(a, b);
    float ea = expf(__fsub_rn(a, mx));
    float eb = expf(__fsub_rn(b, mx));
    float s = __fdiv_rn(eb, __fadd_rn(ea, eb));  // jax.nn.softmax(...)[1]
    SM.f[j] = s;
    cnt += (s > 0.5f) ? 1 : 0;
  }
  *(float4*)(se0 + base) = O0.v[0]; *(float4*)(se0 + base + 4) = O0.v[1];
  *(float4*)(se1 + base) = O1.v[0]; *(float4*)(se1 + base + 4) = O1.v[1];
  *(float4*)(smw + base) = SM.v[0]; *(float4*)(smw + base + 4) = SM.v[1];
  *(ull*)(inst + base) = 0ull;
  ull r = blk_red_add((ull)cnt, lred);
  if (threadIdx.x == 0) atomicAdd(&hdr->remaining, (int)r);
}

__global__ __launch_bounds__(BLKT) void k_loop(
    const float* __restrict__ pred,
    const float* __restrict__ se0,
    const float* __restrict__ se1,
    float* __restrict__ smw,
    unsigned char* __restrict__ inst,
    unsigned char* __restrict__ prop,
    Hdr* hdr, ull* pg, int* __restrict__ out)
{
  cg::grid_group grid = cg::this_grid();
  volatile Hdr* vh = (volatile Hdr*)hdr;
  __shared__ ull lred[BLKT / 64];
  __shared__ int lbad[MAXC];
  const int tid = blockIdx.x * BLKT + threadIdx.x;
  const int base = tid * PXT;

  // P0: initial argmax partials (scores = smw if unclustered else 0)
  {
    F8 S;
    S.v[0] = *(const float4*)(smw + base);
    S.v[1] = *(const float4*)(smw + base + 4);
    ull best = 0;
    #pragma unroll
    for (int j = 0; j < PXT; j++) {
      float s = S.f[j];
      float sc = (s > 0.5f) ? s : 0.0f;
      ull pk = ((ull)__float_as_uint(sc) << 32) | (ull)(0xFFFFFFFFu - (unsigned)(base + j));
      if (pk > best) best = pk;
    }
    best = blk_red_max(best, lred);
    if (threadIdx.x == 0) pg[blockIdx.x] = best;
  }
  grid.sync();

  bool first = true;
  for (int it = 0; it < 1000000; ++it) {
    // ---- S3: finish previous iteration + loop-cond + next-seed setup (block 0)
    if (blockIdx.x == 0) {
      ull v = (threadIdx.x < GRIDB) ? pg[threadIdx.x] : 0ull;
      ull best = blk_red_max(v, lred);
      if (threadIdx.x == 0) {
        int count = hdr->count;
        int rem = hdr->remaining;
        if (!first) {
          int ps = vh->ps, uip = vh->uip;
          bool acc = (ps > 160) &&
                     (__fdiv_rn((float)uip, fmaxf((float)ps, 1.0f)) > 0.5f);
          if (acc) { hdr->prev[count] = ps; count++; hdr->count = count; }
          rem -= (1 + uip);             // seed + unclustered proposal pixels removed
          hdr->remaining = rem;
        }
        bool cont = (rem > 160) && (count < MAXC);
        float score = __uint_as_float((unsigned)(best >> 32));
        int sidx = (int)(0xFFFFFFFFu - (unsigned)(best & 0xFFFFFFFFull));
        if (!cont || score < 0.5f) {
          hdr->stop = 1;
        } else {
          hdr->seed_idx = sidx;
          hdr->c0 = se0[sidx];
          hdr->c1 = se1[sidx];
          hdr->s0 = expf(__fmul_rn(pred[2 * NPIX + sidx], 10.0f));
          hdr->s1 = expf(__fmul_rn(pred[3 * NPIX + sidx], 10.0f));
          hdr->ps = 0; hdr->uip = 0;
        }
      }
    }
    grid.sync();
    if (vh->stop) break;
    first = false;

    // ---- S1: proposal mask + exact integer reductions
    {
      const float c0 = vh->c0, c1 = vh->c1, s0 = vh->s0, s1 = vh->s1;
      const int seed = vh->seed_idx;
      F8 A, B, S;
      A.v[0] = *(const float4*)(se0 + base); A.v[1] = *(const float4*)(se0 + base + 4);
      B.v[0] = *(const float4*)(se1 + base); B.v[1] = *(const float4*)(se1 + base + 4);
      S.v[0] = *(const float4*)(smw + base); S.v[1] = *(const float4*)(smw + base + 4);
      union { unsigned char b[8]; ull u; } P;
      int psl = 0, uipl = 0;
      #pragma unroll
      for (int j = 0; j < PXT; j++) {
        float d0 = __fsub_rn(A.f[j], c0);
        float d1 = __fsub_rn(B.f[j], c1);
        // t = d0*d0*s0 + d1*d1*s1, no FMA contraction (match XLA rounding)
        float t = __fadd_rn(__fmul_rn(__fmul_rn(d0, d0), s0),
                            __fmul_rn(__fmul_rn(d1, d1), s1));
        float dist = expf(-t);
        float s = S.f[j];
        bool pr = (dist > 0.5f) && (fabsf(s) > 0.5f);   // dist>thresh && m
        P.b[j] = pr ? 1 : 0;
        psl += pr ? 1 : 0;
        uipl += (pr && (s > 0.5f) && ((base + j) != seed)) ? 1 : 0;
      }
      *(ull*)(prop + base) = P.u;
      ull r = blk_red_add(((ull)(unsigned)psl << 32) | (unsigned)uipl, lred);
      if (threadIdx.x == 0) {
        atomicAdd(&hdr->ps, (int)(r >> 32));
        atomicAdd(&hdr->uip, (int)(r & 0xFFFFFFFFull));
      }
    }
    grid.sync();

    // ---- S2: apply accept/removal + next-iteration argmax partials (fused)
    {
      int ps = vh->ps, uip = vh->uip;
      bool acc = (ps > 160) &&
                 (__fdiv_rn((float)uip, fmaxf((float)ps, 1.0f)) > 0.5f);
      unsigned char label = (unsigned char)vh->count;
      F8 S;
      S.v[0] = *(const float4*)(smw + base); S.v[1] = *(const float4*)(smw + base + 4);
      ull pu = *(const ull*)(prop + base);
      ull best = 0;
      bool dirty = false;
      #pragma unroll
      for (int j = 0; j < PXT; j++) {
        float s = S.f[j];
        if ((pu >> (8 * j)) & 1) {
          if (acc) inst[base + j] = label;
          if (s > 0.5f) { s = -s; S.f[j] = s; dirty = true; }  // remove from unclustered
        }
        float sc = (s > 0.5f) ? s : 0.0f;
        ull pk = ((ull)__float_as_uint(sc) << 32) | (ull)(0xFFFFFFFFu - (unsigned)(base + j));
        if (pk > best) best = pk;
      }
      if (dirty) {
        *(float4*)(smw + base) = S.v[0];
        *(float4*)(smw + base + 4) = S.v[1];
      }
      best = blk_red_max(best, lred);
      if (threadIdx.x == 0) pg[blockIdx.x] = best;
    }
    grid.sync();
  }

  // ---- Epilogue: bincount -> bad filter -> output write (int32 labels)
  for (int c = threadIdx.x; c < MAXC; c += BLKT) lbad[c] = 0;
  __syncthreads();
  #pragma unroll
  for (int j = 0; j < PXT; j++) atomicAdd(&lbad[inst[base + j]], 1);
  __syncthreads();
  for (int c = threadIdx.x; c < MAXC; c += BLKT)
    if (lbad[c]) atomicAdd(&hdr->now[c], lbad[c]);
  grid.sync();
  if (blockIdx.x == 0 && threadIdx.x < MAXC) {
    int c = threadIdx.x;
    int nowv = hdr->now[c], prevv = hdr->prev[c];
    float ratio = __fdiv_rn((float)nowv, (float)(prevv > 1 ? prevv : 1));
    int b = (nowv != prevv) && (nowv > 0) && ((nowv < 3 * 160) || (ratio < 0.5f));
    if (c == 0) b = 0;
    hdr->bad[c] = b;
  }
  grid.sync();
  {
    for (int c = threadIdx.x; c < MAXC; c += BLKT) lbad[c] = hdr->bad[c];
    __syncthreads();
    I8 O;
    #pragma unroll
    for (int j = 0; j < PXT; j++) {
      int v = inst[base + j];
      O.f[j] = lbad[v] ? 0 : v;
    }
    *(int4*)(out + base) = O.v[0];
    *(int4*)(out + base + 4) = O.v[1];
  }
}

extern "C" void kernel_launch(void* const* d_in, const int* in_sizes, int n_in,
                              void* d_out, int out_size, void* d_ws, size_t ws_size,
                              hipStream_t stream) {
  const float* pred = (const float*)d_in[0];
  char* ws = (char*)d_ws;
  size_t off = 0;
  Hdr* hdr = (Hdr*)(ws + off);              off += ((sizeof(Hdr) + 255) / 256) * 256;
  ull* pg = (ull*)(ws + off);               off += GRIDB * sizeof(ull);
  // pad to 16B
  off = (off + 15) & ~(size_t)15;
  float* se0 = (float*)(ws + off);          off += (size_t)NPIX * 4;
  float* se1 = (float*)(ws + off);          off += (size_t)NPIX * 4;
  float* smw = (float*)(ws + off);          off += (size_t)NPIX * 4;
  unsigned char* inst = (unsigned char*)(ws + off); off += (size_t)NPIX;
  unsigned char* prop = (unsigned char*)(ws + off); off += (size_t)NPIX;
  int* out = (int*)d_out;

  hipLaunchKernelGGL(k_init, dim3(1), dim3(256), 0, stream, hdr);
  hipLaunchKernelGGL(k_pre, dim3(GRIDB), dim3(BLKT), 0, stream,
                     pred, se0, se1, smw, inst, hdr);

  void* args[] = {(void*)&pred, (void*)&se0, (void*)&se1, (void*)&smw,
                  (void*)&inst, (void*)&prop, (void*)&hdr, (void*)&pg, (void*)&out};
  hipLaunchCooperativeKernel((const void*)k_loop, dim3(GRIDB), dim3(BLKT),
                             args, 0, stream);
}

// Round 3
// 64.796 us; speedup vs baseline: 4.7515x; 4.7515x over previous
//
#include <hip/hip_runtime.h>
#include <cstddef>

typedef unsigned long long ull;

#define HH 1024
#define WW 2048
#define NPIX (HH * WW)
#define MAXC 200
#define GRIDB 256
#define BLKT 1024
#define PXT 8                      // pixels per thread, consecutive
#define TAGSH 52
#define DMASK ((1ull << 52) - 1)

union F8 { float4 v[2]; float f[8]; };
union I8 { int4 v[2]; int f[8]; };

__device__ inline ull shfl_down_u64(ull v, int o) {
  unsigned lo = (unsigned)v, hi = (unsigned)(v >> 32);
  lo = __shfl_down(lo, o, 64);
  hi = __shfl_down(hi, o, 64);
  return ((ull)hi << 32) | lo;
}
__device__ inline ull wred_max(ull v) {
  #pragma unroll
  for (int o = 32; o > 0; o >>= 1) { ull u = shfl_down_u64(v, o); if (u > v) v = u; }
  return v;
}
__device__ inline ull wred_add(ull v) {
  #pragma unroll
  for (int o = 32; o > 0; o >>= 1) v += shfl_down_u64(v, o);
  return v;
}
// packed argmax partial: [score:31][~idx:21]  (score >= 0 so sign bit is 0)
__device__ inline ull pk_arg(float sc, int idx) {
  return ((ull)__float_as_uint(sc) << 21) | (ull)(0x1FFFFFu - (unsigned)idx);
}
__device__ inline ull spin_tag(ull* slot, unsigned tg) {
  ull v;
  do {
    v = __hip_atomic_load(slot, __ATOMIC_RELAXED, __HIP_MEMORY_SCOPE_AGENT);
  } while ((unsigned)(v >> TAGSH) != tg);
  return v & DMASK;
}

__global__ __launch_bounds__(BLKT) void k_all(
    const float* __restrict__ pred,
    float* __restrict__ se0p, float* __restrict__ se1p,
    int* __restrict__ prevp, int* __restrict__ nowp,
    ull* pgA, ull* paB, int* __restrict__ out)
{
  __shared__ ull lredM[16], lredA[16];
  __shared__ ull lbc[2];
  __shared__ float lpar[4];
  __shared__ int lbad[MAXC];

  const int b = blockIdx.x;
  const int tid = threadIdx.x;
  const int wid = tid >> 6, lane = tid & 63;
  const int base = (b * BLKT + tid) * PXT;

  // ---------------- pre-phase: se/seed compute, all state -> registers ----
  F8 Av, Bv, Sv;          // spatial_emb x/y, seed-score (sign = clustered flag)
  ull iv = 0;             // 8 inst labels (bytes)
  ull pp = 0;             // prop bits of previous iteration (0x01 bytes)
  {
    F8 P0, P1, P5, P6;
    P0.v[0] = *(const float4*)(pred + base);            P0.v[1] = *(const float4*)(pred + base + 4);
    P1.v[0] = *(const float4*)(pred + NPIX + base);     P1.v[1] = *(const float4*)(pred + NPIX + base + 4);
    P5.v[0] = *(const float4*)(pred + 5 * NPIX + base); P5.v[1] = *(const float4*)(pred + 5 * NPIX + base + 4);
    P6.v[0] = *(const float4*)(pred + 6 * NPIX + base); P6.v[1] = *(const float4*)(pred + 6 * NPIX + base + 4);
    const int h = base >> 11;
    const int wb = base & (WW - 1);
    const float yv = __fmul_rn((float)h, 1.0f / 1023.0f);
    int cnt = 0; ull amax = 0;
    #pragma unroll
    for (int j = 0; j < PXT; j++) {
      Av.f[j] = __fadd_rn(tanhf(P0.f[j]), __fmul_rn((float)(wb + j), 2.0f / 2047.0f));
      Bv.f[j] = __fadd_rn(tanhf(P1.f[j]), yv);
      float a = P5.f[j], bb = P6.f[j];
      float mx = fmaxf(a, bb);
      float ea = expf(__fsub_rn(a, mx));
      float eb = expf(__fsub_rn(bb, mx));
      float s = __fdiv_rn(eb, __fadd_rn(ea, eb));
      Sv.f[j] = s;
      cnt += (s > 0.5f) ? 1 : 0;
      float sc = (s > 0.5f) ? s : 0.0f;
      ull pk = pk_arg(sc, base + j);
      if (pk > amax) amax = pk;
    }
    *(float4*)(se0p + base) = Av.v[0]; *(float4*)(se0p + base + 4) = Av.v[1];
    *(float4*)(se1p + base) = Bv.v[0]; *(float4*)(se1p + base + 4) = Bv.v[1];
    if (b == 0) for (int c = tid; c < MAXC; c += BLKT) nowp[c] = 0;
    __syncthreads();
    ull wm = wred_max(amax), wa = wred_add((ull)(unsigned)cnt);
    if (lane == 0) { lredM[wid] = wm; lredA[wid] = wa; }
    __syncthreads();
    if (tid == 0) {
      ull M = lredM[0]; for (int i = 1; i < 16; i++) if (lredM[i] > M) M = lredM[i];
      ull C = 0;        for (int i = 0; i < 16; i++) C += lredA[i];
      // tag 0 | argmax-partial. RELEASE flushes this block's se writes to the coherent point.
      __hip_atomic_store(&pgA[b], M, __ATOMIC_RELEASE, __HIP_MEMORY_SCOPE_AGENT);
      __hip_atomic_store(&paB[b], (0xFFFull << TAGSH) | C, __ATOMIC_RELAXED, __HIP_MEMORY_SCOPE_AGENT);
    }
  }

  // ---------------- main loop: ONE tag-barrier per iteration -------------
  int count = 1, rem = 0, labP = 0, tstop = 0;
  bool accP = false;
  for (int t = 0;; ++t) {
    const unsigned tg = (unsigned)t & 0xFFFu;
    ull gd = 0, pdv = 0;
    if (tid < GRIDB) {
      gd = spin_tag(&pgA[tid], tg);
    } else if (tid < 2 * GRIDB) {
      unsigned ptg = (t == 0) ? 0xFFFu : ((unsigned)(t - 1) & 0xFFFu);
      ull v = spin_tag(&paB[tid - GRIDB], ptg);
      pdv = (((v >> 14) & 0x3FFFull) << 32) | (v & 0x3FFFull);   // [ps:32|uip:32] wide
    }
    if (wid < 4)      { ull w = wred_max(gd);  if (lane == 0) lredM[wid] = w; }
    else if (wid < 8) { ull w = wred_add(pdv); if (lane == 0) lredA[wid - 4] = w; }
    __syncthreads();
    if (tid == 0) {
      ull M = lredM[0];
      for (int i = 1; i < 4; i++) if (lredM[i] > M) M = lredM[i];
      ull S = lredA[0] + lredA[1] + lredA[2] + lredA[3];
      lbc[0] = M; lbc[1] = S;
    }
    __syncthreads();
    const ull M = lbc[0], S = lbc[1];

    if (t == 0) {
      rem = (int)(S & 0xFFFFFFFFull);           // initial unclustered count
      accP = false; labP = 0;
    } else {
      int ps = (int)(S >> 32), uip = (int)(S & 0xFFFFFFFFull);
      accP = (ps > 160) &&
             (__fdiv_rn((float)uip, fmaxf((float)ps, 1.0f)) > 0.5f);
      labP = count;
      if (accP) {
        if (b == 0 && tid == 0)
          __hip_atomic_store(&prevp[count], ps, __ATOMIC_RELAXED, __HIP_MEMORY_SCOPE_AGENT);
        count++;
      }
      rem -= (1 + uip);
    }
    const unsigned sb = (unsigned)((M >> 21) & 0x7FFFFFFFull);
    const int sidx = 0x1FFFFF - (int)(M & 0x1FFFFFull);
    const float score = __uint_as_float(sb);
    if (!((rem > 160) && (count < MAXC)) || (score < 0.5f)) { tstop = t; break; }

    // deferred labeling of iteration t-1 (register-only byte merge)
    if (accP && pp)
      iv = (iv & ~(pp * 0xFFull)) | (pp * (ull)(unsigned)labP);

    // seed params (immutable arrays; 4 scalar loads -> LDS broadcast)
    if (tid < 4) {
      lpar[tid] = (tid == 0) ? se0p[sidx] : (tid == 1) ? se1p[sidx] :
                  (tid == 2) ? pred[2 * NPIX + sidx] : pred[3 * NPIX + sidx];
    }
    __syncthreads();
    const float c0 = lpar[0], c1 = lpar[1];
    const float s0 = expf(__fmul_rn(lpar[2], 10.0f));
    const float s1 = expf(__fmul_rn(lpar[3], 10.0f));

    // register-only sweep: proposal + removal + next argmax partial
    ull best = 0, npp = 0;
    int psl = 0, uipl = 0;
    #pragma unroll
    for (int j = 0; j < PXT; j++) {
      float d0 = __fsub_rn(Av.f[j], c0);
      float d1 = __fsub_rn(Bv.f[j], c1);
      float tt = __fadd_rn(__fmul_rn(__fmul_rn(d0, d0), s0),
                           __fmul_rn(__fmul_rn(d1, d1), s1));
      float dist = expf(-tt);
      float s = Sv.f[j];
      bool pr = (dist > 0.5f) && (fabsf(s) > 0.5f);
      if (pr) {
        npp |= (0x01ull << (8 * j));
        psl++;
        if (s > 0.5f) {
          if ((base + j) != sidx) uipl++;
          Sv.f[j] = -s;                       // remove from unclustered
        }
      }
      float s2 = Sv.f[j];
      float sc = (s2 > 0.5f) ? s2 : 0.0f;
      ull pk = pk_arg(sc, base + j);
      if (pk > best) best = pk;
    }
    pp = npp;

    ull wm = wred_max(best);
    ull wa = wred_add(((ull)(unsigned)psl << 32) | (unsigned)uipl);
    if (lane == 0) { lredM[wid] = wm; lredA[wid] = wa; }
    __syncthreads();
    if (tid == 0) {
      ull M2 = lredM[0]; for (int i = 1; i < 16; i++) if (lredM[i] > M2) M2 = lredM[i];
      ull S2 = 0;        for (int i = 0; i < 16; i++) S2 += lredA[i];
      int ps = (int)(S2 >> 32), uip = (int)(S2 & 0xFFFFFFFFull);
      __hip_atomic_store(&pgA[b], (((ull)((unsigned)(t + 1) & 0xFFFu)) << TAGSH) | M2,
                         __ATOMIC_RELAXED, __HIP_MEMORY_SCOPE_AGENT);
      __hip_atomic_store(&paB[b], (((ull)tg) << TAGSH) | ((ull)(unsigned)ps << 14) | (ull)(unsigned)uip,
                         __ATOMIC_RELAXED, __HIP_MEMORY_SCOPE_AGENT);
    }
    __syncthreads();   // protect lredM/lredA/lbc from next-phase overwrite
  }

  // ---------------- epilogue: deferred label, bincount, bad filter -------
  for (int c = tid; c < MAXC; c += BLKT) lbad[c] = 0;
  __syncthreads();
  if (accP && pp)
    iv = (iv & ~(pp * 0xFFull)) | (pp * (ull)(unsigned)labP);
  #pragma unroll
  for (int j = 0; j < PXT; j++)
    atomicAdd(&lbad[(int)((iv >> (8 * j)) & 0xFFull)], 1);
  __syncthreads();
  for (int c = tid; c < MAXC; c += BLKT)
    if (lbad[c]) atomicAdd(&nowp[c], lbad[c]);
  __syncthreads();                              // drains this block's atomics
  if (tid == 0)
    __hip_atomic_store(&paB[b], (((ull)((unsigned)tstop & 0xFFFu)) << TAGSH) | 1ull,
                       __ATOMIC_RELAXED, __HIP_MEMORY_SCOPE_AGENT);
  if (tid < GRIDB) (void)spin_tag(&paB[tid], (unsigned)tstop & 0xFFFu);
  __syncthreads();
  for (int c = tid; c < MAXC; c += BLKT) {
    int nw = __hip_atomic_load(&nowp[c], __ATOMIC_RELAXED, __HIP_MEMORY_SCOPE_AGENT);
    int pv = __hip_atomic_load(&prevp[c], __ATOMIC_RELAXED, __HIP_MEMORY_SCOPE_AGENT);
    float ratio = __fdiv_rn((float)nw, (float)(pv > 1 ? pv : 1));
    int bd = (nw != pv) && (nw > 0) && ((nw < 3 * 160) || (ratio < 0.5f));
    if (c == 0) bd = 0;
    lbad[c] = bd;
  }
  __syncthreads();
  {
    I8 O;
    #pragma unroll
    for (int j = 0; j < PXT; j++) {
      int v = (int)((iv >> (8 * j)) & 0xFFull);
      O.f[j] = lbad[v] ? 0 : v;
    }
    *(int4*)(out + base) = O.v[0];
    *(int4*)(out + base + 4) = O.v[1];
  }
}

extern "C" void kernel_launch(void* const* d_in, const int* in_sizes, int n_in,
                              void* d_out, int out_size, void* d_ws, size_t ws_size,
                              hipStream_t stream) {
  const float* pred = (const float*)d_in[0];
  char* ws = (char*)d_ws;
  size_t off = 0;
  ull* pgA = (ull*)(ws + off);   off += GRIDB * sizeof(ull);
  ull* paB = (ull*)(ws + off);   off += GRIDB * sizeof(ull);
  int* prevp = (int*)(ws + off); off += MAXC * sizeof(int);
  int* nowp = (int*)(ws + off);  off += MAXC * sizeof(int);
  off = (off + 255) & ~(size_t)255;
  float* se0 = (float*)(ws + off); off += (size_t)NPIX * 4;
  float* se1 = (float*)(ws + off); off += (size_t)NPIX * 4;
  int* out = (int*)d_out;

  void* args[] = {(void*)&pred, (void*)&se0, (void*)&se1,
                  (void*)&prevp, (void*)&nowp, (void*)&pgA, (void*)&paB, (void*)&out};
  hipLaunchCooperativeKernel((const void*)k_all, dim3(GRIDB), dim3(BLKT),
                             args, 0, stream);
}

// Round 4
// 52.050 us; speedup vs baseline: 5.9151x; 1.2449x over previous
//
#include <hip/hip_runtime.h>
#include <cstddef>

typedef unsigned long long ull;

#define NPIX (1024 * 2048)
#define WW 2048
#define MAXC 200
#define GRIDB 256
#define BLKT 1024
#define PXT 8
#define TAGSH 52
#define DMASK ((1ull << TAGSH) - 1)
#define TCAP 2000   // < 0xAAA so 0xAA-poisoned stale tags can never alias a live tag

union F8 { float4 v[2]; float f[8]; };
union I8 { int4 v[2]; int f[8]; };

__device__ inline ull AL(ull* p) { return __hip_atomic_load(p, __ATOMIC_RELAXED, __HIP_MEMORY_SCOPE_AGENT); }
__device__ inline void AS(ull* p, ull v) { __hip_atomic_store(p, v, __ATOMIC_RELAXED, __HIP_MEMORY_SCOPE_AGENT); }
__device__ inline void ASI(int* p, int v) { __hip_atomic_store(p, v, __ATOMIC_RELAXED, __HIP_MEMORY_SCOPE_AGENT); }
__device__ inline int ALI(int* p) { return __hip_atomic_load(p, __ATOMIC_RELAXED, __HIP_MEMORY_SCOPE_AGENT); }

__device__ inline ull shfl_down_u64(ull v, int o) {
  unsigned lo = (unsigned)v, hi = (unsigned)(v >> 32);
  lo = __shfl_down(lo, o, 64);
  hi = __shfl_down(hi, o, 64);
  return ((ull)hi << 32) | lo;
}

// wave tuple-reduce: argmax-by-k carrying (x,y,w); field-wise sum of z. Lane-0 result.
__device__ inline void tup_wred(ull& k, ull& x, ull& y, ull& w, ull& z) {
  #pragma unroll
  for (int o = 32; o > 0; o >>= 1) {
    ull k2 = shfl_down_u64(k, o), x2 = shfl_down_u64(x, o), y2 = shfl_down_u64(y, o),
        w2 = shfl_down_u64(w, o), z2 = shfl_down_u64(z, o);
    if (k2 > k) { k = k2; x = x2; y = y2; w = w2; }
    z += z2;
  }
}

// payload packing: c0(32) c1(32) e0(32) e1(32) into 3x 52-bit words
__device__ inline void pack3(float c0, float c1, float e0, float e1, ull& X, ull& Y, ull& W) {
  ull b0 = __float_as_uint(c0), b1 = __float_as_uint(c1),
      b2 = __float_as_uint(e0), b3 = __float_as_uint(e1);
  X = (b0 << 20) | (b1 >> 12);
  Y = ((b1 & 0xFFFull) << 40) | (b2 << 8) | (b3 >> 24);
  W = (b3 & 0xFFFFFFull) << 28;
}

// packed argmax key: [score:31][~idx:21]
__device__ inline ull pk_arg(float sc, int idx) {
  return ((ull)__float_as_uint(sc) << 21) | (ull)(0x1FFFFFu - (unsigned)idx);
}

__global__ __launch_bounds__(BLKT) void k_all(
    const float* __restrict__ pred,
    ull* __restrict__ slots,        // [GRIDB][8]: K,X,Y,W,Z per block, one cache line
    int* __restrict__ prevp, int* __restrict__ nowp,
    int* __restrict__ out)
{
  __shared__ ull lsa[4][5];    // spin-phase wave partials
  __shared__ ull lsb[16][5];   // sweep-phase wave partials
  __shared__ int lbad[MAXC];

  const int b = blockIdx.x;
  const int tid = threadIdx.x;
  const int wid = tid >> 6, lane = tid & 63;
  const int base = (b * BLKT + tid) * PXT;

  // ---------------- pre-phase: everything -> registers -------------------
  F8 Av, Bv, Sv, E0, E1;
  ull iv = 0;      // 8 inst labels (bytes)
  ull pp = 0;      // previous iteration's proposal bits (0x01 bytes)
  {
    F8 P0, P1, P2, P3, P5, P6;
    P0.v[0] = *(const float4*)(pred + base);            P0.v[1] = *(const float4*)(pred + base + 4);
    P1.v[0] = *(const float4*)(pred + NPIX + base);     P1.v[1] = *(const float4*)(pred + NPIX + base + 4);
    P2.v[0] = *(const float4*)(pred + 2 * NPIX + base); P2.v[1] = *(const float4*)(pred + 2 * NPIX + base + 4);
    P3.v[0] = *(const float4*)(pred + 3 * NPIX + base); P3.v[1] = *(const float4*)(pred + 3 * NPIX + base + 4);
    P5.v[0] = *(const float4*)(pred + 5 * NPIX + base); P5.v[1] = *(const float4*)(pred + 5 * NPIX + base + 4);
    P6.v[0] = *(const float4*)(pred + 6 * NPIX + base); P6.v[1] = *(const float4*)(pred + 6 * NPIX + base + 4);
    const int h = base >> 11;
    const int wb = base & (WW - 1);
    const float yv = __fmul_rn((float)h, 1.0f / 1023.0f);
    int cnt = 0;
    ull best = 0; float bc0 = 0, bc1 = 0, be0 = 0, be1 = 0;
    #pragma unroll
    for (int j = 0; j < PXT; j++) {
      Av.f[j] = __fadd_rn(tanhf(P0.f[j]), __fmul_rn((float)(wb + j), 2.0f / 2047.0f));
      Bv.f[j] = __fadd_rn(tanhf(P1.f[j]), yv);
      E0.f[j] = expf(__fmul_rn(P2.f[j], 10.0f));
      E1.f[j] = expf(__fmul_rn(P3.f[j], 10.0f));
      float a = P5.f[j], bb = P6.f[j];
      float mx = fmaxf(a, bb);
      float ea = expf(__fsub_rn(a, mx));
      float eb = expf(__fsub_rn(bb, mx));
      float s = __fdiv_rn(eb, __fadd_rn(ea, eb));
      Sv.f[j] = s;
      cnt += (s > 0.5f) ? 1 : 0;
      float sc = (s > 0.5f) ? s : 0.0f;
      ull pk = pk_arg(sc, base + j);
      if (pk > best) { best = pk; bc0 = Av.f[j]; bc1 = Bv.f[j]; be0 = E0.f[j]; be1 = E1.f[j]; }
    }
    ull px, py, pw;
    pack3(bc0, bc1, be0, be1, px, py, pw);
    ull pz = ((ull)(unsigned)cnt << 26);      // ps-field = block m-count, uip 0
    ull pk_ = best;
    tup_wred(pk_, px, py, pw, pz);
    if (lane == 0) { lsb[wid][0] = pk_; lsb[wid][1] = px; lsb[wid][2] = py; lsb[wid][3] = pw; lsb[wid][4] = pz; }
    if (b == 0) {                              // zero the cross-block tallies (atomics -> coherent point)
      for (int c = tid; c < MAXC; c += BLKT) { ASI(&nowp[c], 0); ASI(&prevp[c], 0); }
    }
    __syncthreads();                           // drains zeroing before publish
    if (tid == 0) {
      ull K2 = lsb[0][0], X2 = lsb[0][1], Y2 = lsb[0][2], W2 = lsb[0][3], Z2 = lsb[0][4];
      for (int i = 1; i < 16; i++) {
        ull kk = lsb[i][0];
        if (kk > K2) { K2 = kk; X2 = lsb[i][1]; Y2 = lsb[i][2]; W2 = lsb[i][3]; }
        Z2 += lsb[i][4];
      }
      ull* sl = slots + b * 8;                 // tag 0 publish; K last
      AS(sl + 4, Z2); AS(sl + 3, W2); AS(sl + 2, Y2); AS(sl + 1, X2); AS(sl + 0, K2);
    }
  }

  // ---------------- main loop: ONE tagged barrier per iteration ----------
  int count = 1, rem = 0, tstop = 0;
  for (int t = 0; t < TCAP; ++t) {
    const unsigned tg = (unsigned)t;
    // spin phase: threads 0..255 poll block tid's 5-word line
    if (tid < GRIDB) {
      ull* sl = slots + tid * 8;
      ull k, x, y, w, z;
      for (;;) {
        k = AL(sl + 0); x = AL(sl + 1); y = AL(sl + 2); w = AL(sl + 3); z = AL(sl + 4);
        if (((unsigned)(k >> TAGSH) == tg) & ((unsigned)(x >> TAGSH) == tg) &
            ((unsigned)(y >> TAGSH) == tg) & ((unsigned)(w >> TAGSH) == tg) &
            ((unsigned)(z >> TAGSH) == tg)) break;
      }
      k &= DMASK; x &= DMASK; y &= DMASK; w &= DMASK; z &= DMASK;
      tup_wred(k, x, y, w, z);
      if (lane == 0) { lsa[wid][0] = k; lsa[wid][1] = x; lsa[wid][2] = y; lsa[wid][3] = w; lsa[wid][4] = z; }
    }
    __syncthreads();   // S1
    // all-thread redundant final reduce (LDS broadcast reads)
    ull K = lsa[0][0], X = lsa[0][1], Y = lsa[0][2], W = lsa[0][3], Z = lsa[0][4];
    #pragma unroll
    for (int i = 1; i < 4; i++) {
      ull kk = lsa[i][0], xx = lsa[i][1], yy = lsa[i][2], ww = lsa[i][3], zz = lsa[i][4];
      if (kk > K) { K = kk; X = xx; Y = yy; W = ww; }
      Z += zz;
    }
    // bookkeeping (redundant per-thread, deterministic)
    const int psS = (int)((Z >> 26) & 0x3FFFFFF), uipS = (int)(Z & 0x3FFFFFF);
    bool accP = false; int labP = 0;
    if (t == 0) {
      rem = psS;                                   // initial unclustered count
    } else {
      accP = (psS > 160) &&
             (__fdiv_rn((float)uipS, fmaxf((float)psS, 1.0f)) > 0.5f);
      labP = count;
      if (accP) {
        if (b == 0 && tid == 0) ASI(&prevp[count], psS);
        count++;
      }
      rem -= (1 + uipS);
    }
    // deferred labeling of iteration t-1 (before possible break)
    if (accP && pp)
      iv = (iv & ~(pp * 0xFFull)) | (pp * (ull)(unsigned)labP);
    const float score = __uint_as_float((unsigned)((K >> 21) & 0x7FFFFFFF));
    const int sidx = 0x1FFFFF - (int)(K & 0x1FFFFF);
    if (!((rem > 160) && (count < MAXC)) || (score < 0.5f)) { tstop = t; break; }

    // unpack winner params (no global loads, no expf on critical path)
    const float c0 = __uint_as_float((unsigned)((X >> 20) & 0xFFFFFFFFull));
    const float c1 = __uint_as_float((unsigned)(((X & 0xFFFFFull) << 12) | ((Y >> 40) & 0xFFFull)));
    const float s0 = __uint_as_float((unsigned)((Y >> 8) & 0xFFFFFFFFull));
    const float s1 = __uint_as_float((unsigned)(((Y & 0xFFull) << 24) | ((W >> 28) & 0xFFFFFFull)));

    // register-only sweep: proposal + removal + next argmax partial
    ull best = 0, npp = 0;
    int psl = 0, uipl = 0;
    float bc0 = 0, bc1 = 0, be0 = 0, be1 = 0;
    #pragma unroll
    for (int j = 0; j < PXT; j++) {
      float d0 = __fsub_rn(Av.f[j], c0);
      float d1 = __fsub_rn(Bv.f[j], c1);
      float tt = __fadd_rn(__fmul_rn(__fmul_rn(d0, d0), s0),
                           __fmul_rn(__fmul_rn(d1, d1), s1));
      float dist = expf(-tt);
      float s = Sv.f[j];
      bool pr = (dist > 0.5f) && (fabsf(s) > 0.5f);
      if (pr) {
        npp |= (0x01ull << (8 * j));
        psl++;
        if (s > 0.5f) {
          if ((base + j) != sidx) uipl++;
          s = -s; Sv.f[j] = s;                 // remove from unclustered
        }
      }
      float sc = (s > 0.5f) ? s : 0.0f;
      ull pk = pk_arg(sc, base + j);
      if (pk > best) { best = pk; bc0 = Av.f[j]; bc1 = Bv.f[j]; be0 = E0.f[j]; be1 = E1.f[j]; }
    }
    pp = npp;

    ull px, py, pw;
    pack3(bc0, bc1, be0, be1, px, py, pw);
    ull pz = ((ull)(unsigned)psl << 26) | (ull)(unsigned)uipl;
    ull pk_ = best;
    tup_wred(pk_, px, py, pw, pz);
    if (lane == 0) { lsb[wid][0] = pk_; lsb[wid][1] = px; lsb[wid][2] = py; lsb[wid][3] = pw; lsb[wid][4] = pz; }
    __syncthreads();   // S2
    if (tid == 0) {
      ull K2 = lsb[0][0], X2 = lsb[0][1], Y2 = lsb[0][2], W2 = lsb[0][3], Z2 = lsb[0][4];
      for (int i = 1; i < 16; i++) {
        ull kk = lsb[i][0];
        if (kk > K2) { K2 = kk; X2 = lsb[i][1]; Y2 = lsb[i][2]; W2 = lsb[i][3]; }
        Z2 += lsb[i][4];
      }
      const ull tagw = ((ull)(unsigned)(t + 1)) << TAGSH;
      ull* sl = slots + b * 8;                 // K last so one poll round usually suffices
      AS(sl + 4, tagw | Z2); AS(sl + 3, tagw | W2); AS(sl + 2, tagw | Y2);
      AS(sl + 1, tagw | X2); AS(sl + 0, tagw | K2);
    }
    // no trailing sync needed: lsa rewritten only after next spin completes,
    // which requires this block's publish (t0 past its lsb reads).
  }

  // ---------------- epilogue: bincount(skip 0) -> barrier -> bad -> out --
  for (int c = tid; c < MAXC; c += BLKT) lbad[c] = 0;
  __syncthreads();
  {
    int cur = -1, acc = 0;
    #pragma unroll
    for (int j = 0; j < PXT; j++) {
      int lb = (int)((iv >> (8 * j)) & 0xFFull);
      if (lb == cur) { acc++; }
      else { if (cur > 0) atomicAdd(&lbad[cur], acc); cur = lb; acc = 1; }
    }
    if (cur > 0) atomicAdd(&lbad[cur], acc);
  }
  __syncthreads();
  for (int c = tid + 1; c < MAXC; c += BLKT)   // skip label 0 (bad[0] forced false)
    if (lbad[c]) atomicAdd(&nowp[c], lbad[c]);
  __syncthreads();                             // drains this block's atomics
  {
    const unsigned etg = (unsigned)(tstop + 1);
    if (tid == 0) AS(slots + b * 8, ((ull)etg) << TAGSH);
    if (tid < GRIDB) {
      ull* sl = slots + tid * 8;
      while ((unsigned)(AL(sl) >> TAGSH) != etg) {}
    }
  }
  __syncthreads();
  if (tid < MAXC) {
    int c = tid;
    int nw = (c == 0) ? 0 : ALI(&nowp[c]);
    int pv = ALI(&prevp[c]);
    float ratio = __fdiv_rn((float)nw, (float)(pv > 1 ? pv : 1));
    int bd = (nw != pv) && (nw > 0) && ((nw < 3 * 160) || (ratio < 0.5f));
    if (c == 0) bd = 0;
    lbad[c] = bd;
  }
  __syncthreads();
  {
    I8 O;
    #pragma unroll
    for (int j = 0; j < PXT; j++) {
      int v = (int)((iv >> (8 * j)) & 0xFFull);
      O.f[j] = lbad[v] ? 0 : v;
    }
    *(int4*)(out + base) = O.v[0];
    *(int4*)(out + base + 4) = O.v[1];
  }
}

extern "C" void kernel_launch(void* const* d_in, const int* in_sizes, int n_in,
                              void* d_out, int out_size, void* d_ws, size_t ws_size,
                              hipStream_t stream) {
  const float* pred = (const float*)d_in[0];
  char* ws = (char*)d_ws;
  size_t off = 0;
  ull* slots = (ull*)(ws + off); off += (size_t)GRIDB * 8 * sizeof(ull);
  int* prevp = (int*)(ws + off); off += MAXC * sizeof(int);
  int* nowp  = (int*)(ws + off); off += MAXC * sizeof(int);
  int* out = (int*)d_out;

  hipLaunchKernelGGL(k_all, dim3(GRIDB), dim3(BLKT), 0, stream,
                     pred, slots, prevp, nowp, out);
}